// Round 8
// baseline (326.275 us; speedup 1.0000x reference)
//
#include <hip/hip_runtime.h>

#define NN 50000
#define NE 800000
#define F  128
#define FO 32

#define RSH  8                       // 256-node dst ranges
#define RSZ  256
#define NBKT 196                     // ceil(NN/256)
#define CAP  5120                    // per-bucket capacity (mean 4082 + 16 sigma)
#define PCHUNK 4096                  // edges per partition block
#define NPB  ((NE + PCHUNK - 1) / PCHUNK)   // 196
#define MG   ((NN + 63) / 64)        // fused blocks: 64 rows (4 waves x 16)
#define LGRID ((NN + 3) / 4)         // agg32 blocks (4 waves of 1 node each)

typedef _Float16 h16;
typedef h16   half8 __attribute__((ext_vector_type(8)));
typedef h16   h16x4 __attribute__((ext_vector_type(4)));
typedef h16   h16x2 __attribute__((ext_vector_type(2)));
typedef float f32x4 __attribute__((ext_vector_type(4)));

// ---------------- weight prep: fp32 W[K=128][NC] -> fragment-ordered fp16 hi/lo --
// B-frag for mfma_f32_16x16x32_f16: col n = ct*16+(lane&15), k = kt*32+(lane>>4)*8+j.
// Wf idx: (((part*4+kt)*NCT + ct)*64 + lane)*8 + j.
__device__ __forceinline__ void wprep_one(const float* __restrict__ W,
        h16* __restrict__ Wf, int idx, int NC, int NCT) {
    if (idx >= 128 * NC) return;
    int k = idx / NC, n = idx - k * NC;
    int kt = k >> 5, g = (k & 31) >> 3, j = k & 7;
    int ct = n >> 4;
    int lane = g * 16 + (n & 15);
    float w = W[idx];
    h16 hi = (h16)w;
    h16 lo = (h16)(w - (float)hi);
    int base = ((kt * NCT + ct) * 64 + lane) * 8 + j;
    Wf[base] = hi;
    Wf[base + NCT * 2048] = lo;   // part stride = 4*NCT*64*8
}

// blocks [0,288): weight prep; block 288: zero bucket cursors
__global__ __launch_bounds__(256) void k_pre0(
        const float* __restrict__ S0, const float* __restrict__ N0,
        const float* __restrict__ N1, const float* __restrict__ N2,
        const float* __restrict__ S3, const float* __restrict__ N3,
        h16* fS0, h16* fN0, h16* fN1, h16* fN2, h16* fS3, h16* fN3,
        int* __restrict__ bcur) {
    int bb = blockIdx.x, tid = threadIdx.x;
    if (bb < 256) {
        const float* W = bb < 64 ? S0 : bb < 128 ? N0 : bb < 192 ? N1 : N2;
        h16*        Wf = bb < 64 ? fS0 : bb < 128 ? fN0 : bb < 192 ? fN1 : fN2;
        wprep_one(W, Wf, (bb & 63) * 256 + tid, 128, 8);
    } else if (bb < 288) {
        int b2 = bb - 256;
        const float* W = b2 < 16 ? S3 : N3;
        h16*        Wf = b2 < 16 ? fS3 : fN3;
        wprep_one(W, Wf, (b2 & 15) * 256 + tid, 32, 2);
    } else {
        if (tid < NBKT) bcur[tid] = 0;
    }
}

// ---------------- fp16-split MFMA over NCT column tiles, A-frags in regs --------
template<int NCT>
__device__ __forceinline__ void mfma_cols(const half8* Ahi, const half8* Alo,
        const h16* __restrict__ Wf, h16* __restrict__ out, int row0, int l) {
    const int cdc = l & 15;          // C/D: col = lane&15
    const int cdr = (l >> 4) * 4;    //      row = (lane>>4)*4 + reg   [m89]
    #pragma unroll
    for (int ct = 0; ct < NCT; ++ct) {
        f32x4 acc = {0.f, 0.f, 0.f, 0.f};
        #pragma unroll
        for (int kt = 0; kt < 4; ++kt) {
            half8 bh = *(const half8*)(Wf + (size_t)(((kt * NCT + ct) * 64 + l) * 8));
            half8 bl = *(const half8*)(Wf + (size_t)((((4 + kt) * NCT + ct) * 64 + l) * 8));
            acc = __builtin_amdgcn_mfma_f32_16x16x32_f16(Ahi[kt], bh, acc, 0, 0, 0);
            acc = __builtin_amdgcn_mfma_f32_16x16x32_f16(Alo[kt], bh, acc, 0, 0, 0);
            acc = __builtin_amdgcn_mfma_f32_16x16x32_f16(Ahi[kt], bl, acc, 0, 0, 0);
        }
        #pragma unroll
        for (int r = 0; r < 4; ++r) {
            int gr = row0 + cdr + r;
            if (gr < NN) out[(size_t)gr * (NCT * 16) + ct * 16 + cdc] = (h16)acc[r];
        }
    }
}

// ---------------- fused: produce 16 rows (agg or l2norm) into wave-private LDS,
// then GEMM them through MFMA. No __syncthreads (wave-local tile).
// MODE 0: mean-agg  h = relu(s[v] + agg(g)/max(deg,1) + b)
// MODE 1: gcn-agg   h = relu((agg(g) + g[v])/(deg+1) + b)
// MODE 2: l2norm    h = x[v]/||x[v]||
template<int NCTA, int NCTB, int MODE>
__device__ __forceinline__ void fused_body(int blk, int tid,
        h16* __restrict__ AhiW, h16* __restrict__ AloW,   // [16][136] per wave
        const h16* __restrict__ g, const h16* __restrict__ s,
        const float* __restrict__ x,
        const int* __restrict__ offs, const int* __restrict__ csr,
        const float* __restrict__ degf, const float* __restrict__ bias,
        const h16* __restrict__ WfA, const h16* __restrict__ WfB,
        h16* __restrict__ outA, h16* __restrict__ outB) {
    const int l  = tid & 63;
    const int wv = tid >> 6;
    const int row0 = blk * 64 + wv * 16;

    if constexpr (MODE == 2) {
        #pragma unroll 1
        for (int i = 0; i < 16; ++i) {
            int nd = row0 + i;
            float ox = 0.f, oy = 0.f;
            if (nd < NN) {
                float2 v = ((const float2*)(x + (size_t)nd * F))[l];
                float ss = v.x * v.x + v.y * v.y;
                #pragma unroll
                for (int d = 1; d < 64; d <<= 1) ss += __shfl_xor(ss, d, 64);
                float inv = 1.0f / fmaxf(sqrtf(ss), 1e-12f);
                ox = v.x * inv; oy = v.y * inv;
            }
            h16 hx = (h16)ox, hy = (h16)oy;
            h16x2 vhi = {hx, hy};
            h16x2 vlo = {(h16)(ox - (float)hx), (h16)(oy - (float)hy)};
            *(h16x2*)(AhiW + i * 136 + l * 2) = vhi;
            *(h16x2*)(AloW + i * 136 + l * 2) = vlo;
        }
    } else {
        const int q  = l >> 4;      // row-group 0..3 (4 gather rows / instr)
        const int li = l & 15;      // half8 slot within the 256B row
        const half8* g8 = (const half8*)g;
        #pragma unroll 1
        for (int i = 0; i < 16; ++i) {
            int nd = row0 + i;
            float r[8] = {0.f, 0.f, 0.f, 0.f, 0.f, 0.f, 0.f, 0.f};
            if (nd < NN) {
                const int beg = offs[nd], end = offs[nd + 1];
                float a0[8], a1[8];
                #pragma unroll
                for (int j = 0; j < 8; ++j) { a0[j] = 0.f; a1[j] = 0.f; }
                int e = beg;
                for (; e + 16 <= end; e += 16) {    // 16 rows in flight
                    int u0 = csr[e + q];
                    int u1 = csr[e + 4 + q];
                    int u2 = csr[e + 8 + q];
                    int u3 = csr[e + 12 + q];
                    half8 v0 = g8[(size_t)u0 * 16 + li];
                    half8 v1 = g8[(size_t)u1 * 16 + li];
                    half8 v2 = g8[(size_t)u2 * 16 + li];
                    half8 v3 = g8[(size_t)u3 * 16 + li];
                    #pragma unroll
                    for (int j = 0; j < 8; ++j) {
                        a0[j] += (float)v0[j] + (float)v2[j];
                        a1[j] += (float)v1[j] + (float)v3[j];
                    }
                }
                for (; e + 4 <= end; e += 4) {
                    half8 v = g8[(size_t)csr[e + q] * 16 + li];
                    #pragma unroll
                    for (int j = 0; j < 8; ++j) a0[j] += (float)v[j];
                }
                if (q < end - e) {                  // tail 0..3 rows
                    half8 v = g8[(size_t)csr[e + q] * 16 + li];
                    #pragma unroll
                    for (int j = 0; j < 8; ++j) a1[j] += (float)v[j];
                }
                #pragma unroll
                for (int j = 0; j < 8; ++j) {
                    a0[j] += a1[j];
                    a0[j] += __shfl_xor(a0[j], 16, 64);
                    a0[j] += __shfl_xor(a0[j], 32, 64);
                }
                const float dg = degf[nd];
                float bb[8];
                *(float4*)(bb)     = *(const float4*)(bias + li * 8);
                *(float4*)(bb + 4) = *(const float4*)(bias + li * 8 + 4);
                if constexpr (MODE == 0) {
                    float inv = 1.f / fmaxf(dg, 1.f);
                    half8 sv = ((const half8*)s)[(size_t)nd * 16 + li];
                    #pragma unroll
                    for (int j = 0; j < 8; ++j)
                        r[j] = fmaxf((float)sv[j] + a0[j] * inv + bb[j], 0.f);
                } else {
                    float inv = 1.f / (dg + 1.f);
                    half8 gv = g8[(size_t)nd * 16 + li];
                    #pragma unroll
                    for (int j = 0; j < 8; ++j)
                        r[j] = fmaxf((a0[j] + (float)gv[j]) * inv + bb[j], 0.f);
                }
            }
            if (q == 0) {
                half8 vhi, vlo;
                #pragma unroll
                for (int j = 0; j < 8; ++j) {
                    h16 hi = (h16)r[j];
                    vhi[j] = hi;
                    vlo[j] = (h16)(r[j] - (float)hi);
                }
                *(half8*)(AhiW + i * 136 + li * 8) = vhi;
                *(half8*)(AloW + i * 136 + li * 8) = vlo;
            }
        }
    }

    // ---- phase 2: GEMM the wave's 16 rows straight from its LDS tile ----
    half8 Ahi[4], Alo[4];
    const h16* ah = AhiW + (l & 15) * 136 + (l >> 4) * 8;
    const h16* al = AloW + (l & 15) * 136 + (l >> 4) * 8;
    #pragma unroll
    for (int kt = 0; kt < 4; ++kt) {
        Ahi[kt] = *(const half8*)(ah + kt * 32);
        Alo[kt] = *(const half8*)(al + kt * 32);
    }
    mfma_cols<NCTA>(Ahi, Alo, WfA, outA, row0, l);
    if constexpr (NCTB > 0) mfma_cols<NCTB>(Ahi, Alo, WfB, outB, row0, l);
}

template<int NCTA, int NCTB, int MODE>
__global__ __launch_bounds__(256) void k_fused(
        const h16* __restrict__ g, const h16* __restrict__ s,
        const int* __restrict__ offs, const int* __restrict__ csr,
        const float* __restrict__ degf, const float* __restrict__ bias,
        const h16* __restrict__ WfA, const h16* __restrict__ WfB,
        h16* __restrict__ outA, h16* __restrict__ outB) {
    __shared__ h16 Ah[4][16][136];
    __shared__ h16 Al[4][16][136];
    const int wv = threadIdx.x >> 6;
    fused_body<NCTA, NCTB, MODE>(blockIdx.x, threadIdx.x,
        &Ah[wv][0][0], &Al[wv][0][0], g, s, nullptr,
        offs, csr, degf, bias, WfA, WfB, outA, outB);
}

// ---------------- pre1: edge partition (blocks [0,NPB)) ∥ l2norm+GEMM0 (rest) ----
__global__ __launch_bounds__(256) void k_pre1(const int* __restrict__ src,
        const int* __restrict__ dst, int* __restrict__ bcur, int* __restrict__ barea,
        const float* __restrict__ x, const h16* __restrict__ WfS0,
        const h16* __restrict__ WfN0, h16* __restrict__ s16, h16* __restrict__ gh) {
    __shared__ h16 Ah[4][16][136];
    __shared__ h16 Al[4][16][136];
    const int tid = threadIdx.x;
    if ((int)blockIdx.x < NPB) {
        int* cnt  = (int*)&Ah[0][0][0];     // 392 ints << 17408 B
        int* base = cnt + NBKT;
        const int e0 = blockIdx.x * PCHUNK;
        for (int i = tid; i < NBKT; i += 256) cnt[i] = 0;
        __syncthreads();
        #pragma unroll
        for (int k = 0; k < PCHUNK / 256; ++k) {
            int e = e0 + k * 256 + tid;
            if (e < NE) atomicAdd(&cnt[dst[e] >> RSH], 1);
        }
        __syncthreads();
        for (int i = tid; i < NBKT; i += 256)
            base[i] = atomicAdd(&bcur[i], cnt[i]);       // reserve private range
        __syncthreads();
        for (int i = tid; i < NBKT; i += 256) cnt[i] = base[i];   // reuse as cursor
        __syncthreads();
        #pragma unroll
        for (int k = 0; k < PCHUNK / 256; ++k) {
            int e = e0 + k * 256 + tid;
            if (e < NE) {
                int d = dst[e], sv = src[e];
                int b = d >> RSH;
                int p = atomicAdd(&cnt[b], 1);
                barea[b * CAP + p] = ((d & (RSZ - 1)) << 16) | sv;   // src < 2^16
            }
        }
    } else {
        const int wv = tid >> 6;
        fused_body<8, 8, 2>((int)blockIdx.x - NPB, tid,
            &Ah[wv][0][0], &Al[wv][0][0], nullptr, nullptr, x,
            nullptr, nullptr, nullptr, nullptr, WfS0, WfN0, s16, gh);
    }
}

// ---------------- per-bucket: global scan (redundant per block) + hist + fill ----
__global__ __launch_bounds__(256) void k_bfill(const int* __restrict__ barea,
        const int* __restrict__ bcur, int* __restrict__ offs,
        float* __restrict__ degf, int* __restrict__ csr) {
    __shared__ int pre[NBKT];
    __shared__ int hist_cur[RSZ];
    __shared__ int ws[4];
    const int r = blockIdx.x, tid = threadIdx.x;
    const int lane = tid & 63, wv = tid >> 6;
    int bv = (tid < NBKT) ? bcur[tid] : 0;
    int bi = bv;
    #pragma unroll
    for (int d = 1; d < 64; d <<= 1) {
        int t = __shfl_up(bi, d, 64);
        if (lane >= d) bi += t;
    }
    if (lane == 63) ws[wv] = bi;
    __syncthreads();
    if (tid == 0) {
        int run = 0;
        #pragma unroll
        for (int w = 0; w < 4; ++w) { int t = ws[w]; ws[w] = run; run += t; }
    }
    __syncthreads();
    if (tid < NBKT) pre[tid] = ws[wv] + bi - bv;
    if (r == 0 && tid == NBKT - 1) offs[NN] = ws[wv] + bi;   // == NE
    __syncthreads();
    const int nb    = bcur[r];
    const int gbase = pre[r];
    const int node  = (r << RSH) + tid;
    hist_cur[tid] = 0;
    __syncthreads();
    const int* area = barea + r * CAP;
    for (int i = tid; i < nb; i += 256) atomicAdd(&hist_cur[area[i] >> 16], 1);
    __syncthreads();
    const int v = hist_cur[tid];
    int incl = v;
    #pragma unroll
    for (int d = 1; d < 64; d <<= 1) {
        int t = __shfl_up(incl, d, 64);
        if (lane >= d) incl += t;
    }
    __syncthreads();
    if (lane == 63) ws[wv] = incl;
    __syncthreads();
    if (tid == 0) {
        int run = 0;
        #pragma unroll
        for (int w = 0; w < 4; ++w) { int t = ws[w]; ws[w] = run; run += t; }
    }
    __syncthreads();
    const int ex = ws[wv] + incl - v;
    if (node < NN) {
        offs[node] = gbase + ex;
        degf[node] = (float)v;
    }
    __syncthreads();
    hist_cur[tid] = gbase + ex;     // becomes the scatter cursor
    __syncthreads();
    for (int i = tid; i < nb; i += 256) {
        int pk = area[i];
        int p = atomicAdd(&hist_cur[pk >> 16], 1);
        csr[p] = pk & 0xFFFF;
    }
}

// ---------------- final aggregation d=32 (mean, no relu, fp32 out) --------------
__global__ __launch_bounds__(256) void k_agg32(const h16* __restrict__ g,
        const h16* __restrict__ s, const int* __restrict__ offs,
        const int* __restrict__ csr, const float* __restrict__ degf,
        const float* __restrict__ b, float* __restrict__ out) {
    const int wid  = (int)((blockIdx.x * 256 + threadIdx.x) >> 6);
    const int lane = threadIdx.x & 63;
    if (wid >= NN) return;
    const int grp = lane >> 3;          // 8 row-groups
    const int li  = lane & 7;           // h16x4 slot within the 64B row
    const int beg = offs[wid], end = offs[wid + 1];
    const h16x4* g4 = (const h16x4*)g;  // row stride = 8 h16x4
    float a0[4] = {0.f, 0.f, 0.f, 0.f}, a1[4] = {0.f, 0.f, 0.f, 0.f};
    int e = beg + grp;
    for (; e + 8 < end; e += 16) {      // 16 rows in flight
        int u0 = csr[e], u1 = csr[e + 8];
        h16x4 v0 = g4[(size_t)u0 * 8 + li];
        h16x4 v1 = g4[(size_t)u1 * 8 + li];
        #pragma unroll
        for (int j = 0; j < 4; ++j) { a0[j] += (float)v0[j]; a1[j] += (float)v1[j]; }
    }
    if (e < end) {
        h16x4 v = g4[(size_t)csr[e] * 8 + li];
        #pragma unroll
        for (int j = 0; j < 4; ++j) a0[j] += (float)v[j];
    }
    #pragma unroll
    for (int j = 0; j < 4; ++j) {
        a0[j] += a1[j];
        a0[j] += __shfl_xor(a0[j], 8, 64);
        a0[j] += __shfl_xor(a0[j], 16, 64);
        a0[j] += __shfl_xor(a0[j], 32, 64);
    }
    if (grp) return;
    const float inv = 1.f / fmaxf(degf[wid], 1.f);
    float4 bb = ((const float4*)b)[li];
    h16x4 sv = ((const h16x4*)s)[(size_t)wid * 8 + li];
    float4 r;
    r.x = (float)sv[0] + a0[0] * inv + bb.x;
    r.y = (float)sv[1] + a0[1] * inv + bb.y;
    r.z = (float)sv[2] + a0[2] * inv + bb.z;
    r.w = (float)sv[3] + a0[3] * inv + bb.w;
    ((float4*)out)[(size_t)wid * 8 + li] = r;
}

extern "C" void kernel_launch(void* const* d_in, const int* in_sizes, int n_in,
                              void* d_out, int out_size, void* d_ws, size_t ws_size,
                              hipStream_t stream) {
    const float* x       = (const float*)d_in[0];
    const int*   src     = (const int*)  d_in[1];
    const int*   dst     = (const int*)  d_in[2];
    const float* Wself0  = (const float*)d_in[3];
    const float* Wneigh0 = (const float*)d_in[4];
    const float* b0      = (const float*)d_in[5];
    const float* Wneigh1 = (const float*)d_in[6];
    const float* b1      = (const float*)d_in[7];
    const float* Wneigh2 = (const float*)d_in[8];
    const float* b2      = (const float*)d_in[9];
    const float* Wself3  = (const float*)d_in[10];
    const float* Wneigh3 = (const float*)d_in[11];
    const float* b3      = (const float*)d_in[12];
    float* out = (float*)d_out;

    char* ws = (char*)d_ws;
    size_t off = 0;
    auto alloc = [&](size_t bytes) -> void* {
        void* p = ws + off;
        off += (bytes + 255) & ~(size_t)255;
        return p;
    };
    float* degf   = (float*)alloc((size_t)NN * 4);
    int*   offs   = (int*)  alloc((size_t)(NN + 1) * 4);
    int*   csr    = (int*)  alloc((size_t)NE * 4);
    int*   bcur   = (int*)  alloc((size_t)NBKT * 4);
    int*   barea  = (int*)  alloc((size_t)NBKT * CAP * 4);
    h16*   s16    = (h16*)  alloc((size_t)NN * F * 2);   // layer0 self operand
    h16*   ghA    = (h16*)  alloc((size_t)NN * F * 2);   // gather ping
    h16*   ghB    = (h16*)  alloc((size_t)NN * F * 2);   // gather pong
    h16*   s16b   = (h16*)  alloc((size_t)NN * FO * 2);  // layer3 self operand
    h16*   gh4    = (h16*)  alloc((size_t)NN * FO * 2);  // layer3 gather operand
    h16*   WfS0   = (h16*)  alloc((size_t)128 * 128 * 2 * 2);
    h16*   WfN0   = (h16*)  alloc((size_t)128 * 128 * 2 * 2);
    h16*   WfN1   = (h16*)  alloc((size_t)128 * 128 * 2 * 2);
    h16*   WfN2   = (h16*)  alloc((size_t)128 * 128 * 2 * 2);
    h16*   WfS3   = (h16*)  alloc((size_t)128 * 32 * 2 * 2);
    h16*   WfN3   = (h16*)  alloc((size_t)128 * 32 * 2 * 2);

    // 1: weight prep + bucket-cursor zero
    k_pre0<<<289, 256, 0, stream>>>(Wself0, Wneigh0, Wneigh1, Wneigh2,
                                    Wself3, Wneigh3,
                                    WfS0, WfN0, WfN1, WfN2, WfS3, WfN3, bcur);
    // 2: edge partition ∥ (l2norm + GEMM0: h0@S0 -> s16, h0@N0 -> ghA)
    k_pre1<<<NPB + MG, 256, 0, stream>>>(src, dst, bcur, barea, x,
                                         WfS0, WfN0, s16, ghA);
    // 3: per-bucket scan + hist + CSR fill
    k_bfill<<<NBKT, 256, 0, stream>>>(barea, bcur, offs, degf, csr);

    // 4: [agg layer0 (mean) + GEMM1] -> ghB
    k_fused<8, 0, 0><<<MG, 256, 0, stream>>>(ghA, s16, offs, csr, degf, b0,
                                             WfN1, nullptr, ghB, nullptr);
    // 5: [agg layer1 (gcn) + GEMM2] -> ghA
    k_fused<8, 0, 1><<<MG, 256, 0, stream>>>(ghB, nullptr, offs, csr, degf, b1,
                                             WfN2, nullptr, ghA, nullptr);
    // 6: [agg layer2 (gcn) + GEMM3 (S3,N3)] -> s16b, gh4
    k_fused<2, 2, 1><<<MG, 256, 0, stream>>>(ghA, nullptr, offs, csr, degf, b2,
                                             WfS3, WfN3, s16b, gh4);
    // 7: final mean-agg d=32 -> out
    k_agg32<<<LGRID, 256, 0, stream>>>(gh4, s16b, offs, csr, degf, b3, out);
}

// Round 9
// 297.003 us; speedup vs baseline: 1.0986x; 1.0986x over previous
//
#include <hip/hip_runtime.h>

#define NN 50000
#define NE 800000
#define F  128
#define FO 32

#define RSH  8                       // 256-node dst ranges
#define RSZ  256
#define NBKT 196                     // ceil(NN/256)
#define CAP  5120                    // barea per-bucket capacity (raw edges)
#define CAP16 9216                   // csr per-bucket capacity (16-padded; >= 5120+256*15)
#define PCHUNK 4096                  // edges per partition block
#define NPB  ((NE + PCHUNK - 1) / PCHUNK)   // 196
#define MG   ((NN + 63) / 64)        // GEMM blocks: 64 rows (4 waves x 16)
#define LGRID ((NN + 3) / 4)         // agg/l2norm blocks (1 node per wave)

typedef _Float16 h16;
typedef h16   half8 __attribute__((ext_vector_type(8)));
typedef h16   h16x4 __attribute__((ext_vector_type(4)));
typedef h16   h16x2 __attribute__((ext_vector_type(2)));
typedef float f32x4 __attribute__((ext_vector_type(4)));

// ---------------- weight prep: fp32 W[K=128][NC] -> fragment-ordered fp16 hi/lo --
// B-frag for mfma_f32_16x16x32_f16: col n = ct*16+(lane&15), k = kt*32+(lane>>4)*8+j.
// Wf idx: (((part*4+kt)*NCT + ct)*64 + lane)*8 + j.
__device__ __forceinline__ void wprep_one(const float* __restrict__ W,
        h16* __restrict__ Wf, int idx, int NC, int NCT) {
    if (idx >= 128 * NC) return;
    int k = idx / NC, n = idx - k * NC;
    int kt = k >> 5, g = (k & 31) >> 3, j = k & 7;
    int ct = n >> 4;
    int lane = g * 16 + (n & 15);
    float w = W[idx];
    h16 hi = (h16)w;
    h16 lo = (h16)(w - (float)hi);
    int base = ((kt * NCT + ct) * 64 + lane) * 8 + j;
    Wf[base] = hi;
    Wf[base + NCT * 2048] = lo;   // part stride = 4*NCT*64*8
}

// blocks [0,288): weight prep; block 288: zero bucket cursors + sentinel rows
__global__ __launch_bounds__(256) void k_pre0(
        const float* __restrict__ S0, const float* __restrict__ N0,
        const float* __restrict__ N1, const float* __restrict__ N2,
        const float* __restrict__ S3, const float* __restrict__ N3,
        h16* fS0, h16* fN0, h16* fN1, h16* fN2, h16* fS3, h16* fN3,
        int* __restrict__ bcur, h16* __restrict__ ghA, h16* __restrict__ ghB,
        h16* __restrict__ gh4) {
    int bb = blockIdx.x, tid = threadIdx.x;
    if (bb < 256) {
        const float* W = bb < 64 ? S0 : bb < 128 ? N0 : bb < 192 ? N1 : N2;
        h16*        Wf = bb < 64 ? fS0 : bb < 128 ? fN0 : bb < 192 ? fN1 : fN2;
        wprep_one(W, Wf, (bb & 63) * 256 + tid, 128, 8);
    } else if (bb < 288) {
        int b2 = bb - 256;
        const float* W = b2 < 16 ? S3 : N3;
        h16*        Wf = b2 < 16 ? fS3 : fN3;
        wprep_one(W, Wf, (b2 & 15) * 256 + tid, 32, 2);
    } else {
        if (tid < NBKT) bcur[tid] = 0;
        if (tid < F) {                      // zero sentinel row NN (pad target)
            ghA[(size_t)NN * F + tid] = (h16)0.f;
            ghB[(size_t)NN * F + tid] = (h16)0.f;
        }
        if (tid < FO) gh4[(size_t)NN * FO + tid] = (h16)0.f;
    }
}

// ---------------- pre1: edge partition (blocks [0,NPB)) ∥ l2norm (rest) ---------
__global__ __launch_bounds__(256) void k_pre1(const int* __restrict__ src,
        const int* __restrict__ dst, int* __restrict__ bcur, int* __restrict__ barea,
        const float* __restrict__ x, h16* __restrict__ hhi, h16* __restrict__ hlo) {
    __shared__ int cnt[NBKT];
    __shared__ int base[NBKT];
    const int tid = threadIdx.x;
    if ((int)blockIdx.x < NPB) {
        const int e0 = blockIdx.x * PCHUNK;
        for (int i = tid; i < NBKT; i += 256) cnt[i] = 0;
        __syncthreads();
        #pragma unroll
        for (int k = 0; k < PCHUNK / 256; ++k) {
            int e = e0 + k * 256 + tid;
            if (e < NE) atomicAdd(&cnt[dst[e] >> RSH], 1);
        }
        __syncthreads();
        for (int i = tid; i < NBKT; i += 256)
            base[i] = atomicAdd(&bcur[i], cnt[i]);       // reserve private range
        __syncthreads();
        for (int i = tid; i < NBKT; i += 256) cnt[i] = base[i];   // reuse as cursor
        __syncthreads();
        #pragma unroll
        for (int k = 0; k < PCHUNK / 256; ++k) {
            int e = e0 + k * 256 + tid;
            if (e < NE) {
                int d = dst[e], sv = src[e];
                int b = d >> RSH;
                int p = atomicAdd(&cnt[b], 1);
                barea[b * CAP + p] = ((d & (RSZ - 1)) << 16) | sv;   // src < 2^16
            }
        }
    } else {
        const int bb   = blockIdx.x - NPB;
        const int wid  = bb * 4 + (tid >> 6);
        const int lane = tid & 63;
        if (wid >= NN) return;
        const float2* xr = (const float2*)(x + (size_t)wid * F);
        float2 v = xr[lane];
        float ss = v.x * v.x + v.y * v.y;
        #pragma unroll
        for (int d = 1; d < 64; d <<= 1) ss += __shfl_xor(ss, d, 64);
        float inv = 1.0f / fmaxf(sqrtf(ss), 1e-12f);
        float ox = v.x * inv, oy = v.y * inv;
        h16 hx = (h16)ox, hy = (h16)oy;
        h16x2 vhi = {hx, hy};
        h16x2 vlo = {(h16)(ox - (float)hx), (h16)(oy - (float)hy)};
        *(h16x2*)(hhi + (size_t)wid * F + lane * 2) = vhi;
        *(h16x2*)(hlo + (size_t)wid * F + lane * 2) = vlo;
    }
}

// ---------------- fp16-split MFMA GEMM helpers (Ootomo 3-term) -------------------
template<int NCT, bool OUT16>
__device__ __forceinline__ void mfma_cols(const half8* Ahi, const half8* Alo,
        const h16* __restrict__ Wf, void* __restrict__ out, int row0, int l) {
    const int cdc = l & 15;          // C/D: col = lane&15
    const int cdr = (l >> 4) * 4;    //      row = (lane>>4)*4 + reg   [m89]
    #pragma unroll
    for (int ct = 0; ct < NCT; ++ct) {
        f32x4 acc = {0.f, 0.f, 0.f, 0.f};
        #pragma unroll
        for (int kt = 0; kt < 4; ++kt) {
            half8 bh = *(const half8*)(Wf + (size_t)(((kt * NCT + ct) * 64 + l) * 8));
            half8 bl = *(const half8*)(Wf + (size_t)((((4 + kt) * NCT + ct) * 64 + l) * 8));
            acc = __builtin_amdgcn_mfma_f32_16x16x32_f16(Ahi[kt], bh, acc, 0, 0, 0);
            acc = __builtin_amdgcn_mfma_f32_16x16x32_f16(Alo[kt], bh, acc, 0, 0, 0);
            acc = __builtin_amdgcn_mfma_f32_16x16x32_f16(Ahi[kt], bl, acc, 0, 0, 0);
        }
        #pragma unroll
        for (int r = 0; r < 4; ++r) {
            int gr = row0 + cdr + r;
            if (gr < NN) {
                size_t oi = (size_t)gr * (NCT * 16) + ct * 16 + cdc;
                if constexpr (OUT16) ((h16*)out)[oi] = (h16)acc[r];
                else                 ((float*)out)[oi] = acc[r];
            }
        }
    }
}

template<int NCTA, int NCTB>
__device__ __forceinline__ void mfma_block(int blk, int tid,
        const h16* __restrict__ hhi, const h16* __restrict__ hlo,
        const h16* __restrict__ WfA, const h16* __restrict__ WfB,
        h16* __restrict__ outA, h16* __restrict__ outB) {
    const int l  = tid & 63;
    const int wv = tid >> 6;
    const int row0 = blk * 64 + wv * 16;
    int ar = row0 + (l & 15); if (ar >= NN) ar = NN - 1;   // A: row = lane&15
    const size_t ab = (size_t)ar * F + (l >> 4) * 8;       //    k = kt*32+(lane>>4)*8+j
    half8 Ahi[4], Alo[4];
    #pragma unroll
    for (int kt = 0; kt < 4; ++kt) {
        Ahi[kt] = *(const half8*)(hhi + ab + kt * 32);
        Alo[kt] = *(const half8*)(hlo + ab + kt * 32);
    }
    mfma_cols<NCTA, true>(Ahi, Alo, WfA, (void*)outA, row0, l);
    if constexpr (NCTB > 0) mfma_cols<NCTB, true>(Ahi, Alo, WfB, (void*)outB, row0, l);
}

template<int NCTA, int NCTB>
__global__ __launch_bounds__(256) void k_mfma(const h16* __restrict__ hhi,
        const h16* __restrict__ hlo, const h16* __restrict__ WfA,
        const h16* __restrict__ WfB, h16* __restrict__ outA,
        h16* __restrict__ outB) {
    mfma_block<NCTA, NCTB>(blockIdx.x, threadIdx.x, hhi, hlo, WfA, WfB, outA, outB);
}

// ---------------- fused: bucket CSR fill (blocks [0,NBKT)) ∥ GEMM0 (rest) --------
// csr segments are PADDED to multiples of 16 with sentinel NN (zero row), fixed
// per-bucket base r*CAP16 -> no global scan needed; offs[node]=segment start.
__global__ __launch_bounds__(256) void k_bfill_mfma(
        const int* __restrict__ barea, const int* __restrict__ bcur,
        int* __restrict__ offs, float* __restrict__ degf, int* __restrict__ csr,
        const h16* __restrict__ hhi, const h16* __restrict__ hlo,
        const h16* __restrict__ WfA, const h16* __restrict__ WfB,
        h16* __restrict__ outA, h16* __restrict__ outB) {
    __shared__ int hist[RSZ];
    __shared__ int ws[4];
    const int tid = threadIdx.x;
    if ((int)blockIdx.x < NBKT) {
        const int r = blockIdx.x;
        const int lane = tid & 63, wv = tid >> 6;
        const int nb = bcur[r];
        hist[tid] = 0;
        __syncthreads();
        const int* area = barea + r * CAP;
        for (int i = tid; i < nb; i += 256) atomicAdd(&hist[area[i] >> 16], 1);
        __syncthreads();
        const int v   = hist[tid];
        const int psz = (v + 15) & ~15;          // padded segment size
        int incl = psz;
        #pragma unroll
        for (int d = 1; d < 64; d <<= 1) {
            int t = __shfl_up(incl, d, 64);
            if (lane >= d) incl += t;
        }
        if (lane == 63) ws[wv] = incl;
        __syncthreads();
        if (tid == 0) {
            int run = 0;
            #pragma unroll
            for (int w = 0; w < 4; ++w) { int t = ws[w]; ws[w] = run; run += t; }
        }
        __syncthreads();
        const int beg  = r * CAP16 + ws[wv] + incl - psz;
        const int node = (r << RSH) + tid;
        if (node < NN) {
            offs[node] = beg;
            degf[node] = (float)v;
        }
        __syncthreads();
        hist[tid] = beg;                 // becomes the scatter cursor
        __syncthreads();
        for (int i = tid; i < nb; i += 256) {
            int pk = area[i];
            int p = atomicAdd(&hist[pk >> 16], 1);
            csr[p] = pk & 0xFFFF;
        }
        for (int i = v; i < psz; ++i) csr[beg + i] = NN;   // sentinel pads
    } else {
        mfma_block<8, 8>((int)blockIdx.x - NBKT, tid, hhi, hlo, WfA, WfB, outA, outB);
    }
}

// ---------------- aggregation d=128: padded 16-in-flight gather ------------------
// MODE 0: mean  -> relu(s[v] + agg/max(deg,1) + b)     (s fp16)
// MODE 1: gcn   -> relu((agg + g[v])/(deg+1) + b)
template<int MODE>
__global__ __launch_bounds__(256) void k_agg128(const h16* __restrict__ g,
        const h16* __restrict__ s, const int* __restrict__ offs,
        const int* __restrict__ csr, const float* __restrict__ degf,
        const float* __restrict__ b, h16* __restrict__ hhi, h16* __restrict__ hlo) {
    const int wid  = (int)((blockIdx.x * 256 + threadIdx.x) >> 6);
    const int lane = threadIdx.x & 63;
    if (wid >= NN) return;
    const int q  = lane >> 4;       // row-group 0..3 (4 rows per instruction)
    const int li = lane & 15;       // half8 slot within the 256B row
    const int beg = offs[wid];
    const float dgf = degf[wid];
    const int n16 = ((int)dgf + 15) >> 4;
    const half8* g8 = (const half8*)g;      // row stride = 16 half8
    float a0[8], a1[8];
    #pragma unroll
    for (int j = 0; j < 8; ++j) { a0[j] = 0.f; a1[j] = 0.f; }
    for (int t = 0; t < n16; ++t) {         // every batch fully 16-in-flight
        const int e = beg + (t << 4);
        int u0 = csr[e + q];
        int u1 = csr[e + 4 + q];
        int u2 = csr[e + 8 + q];
        int u3 = csr[e + 12 + q];
        half8 v0 = g8[(size_t)u0 * 16 + li];
        half8 v1 = g8[(size_t)u1 * 16 + li];
        half8 v2 = g8[(size_t)u2 * 16 + li];
        half8 v3 = g8[(size_t)u3 * 16 + li];
        #pragma unroll
        for (int j = 0; j < 8; ++j) {
            a0[j] += (float)v0[j] + (float)v2[j];
            a1[j] += (float)v1[j] + (float)v3[j];
        }
    }
    #pragma unroll
    for (int j = 0; j < 8; ++j) {
        a0[j] += a1[j];
        a0[j] += __shfl_xor(a0[j], 16, 64);
        a0[j] += __shfl_xor(a0[j], 32, 64);
    }
    if (q) return;
    float bb[8];
    *(float4*)(bb)     = *(const float4*)(b + li * 8);
    *(float4*)(bb + 4) = *(const float4*)(b + li * 8 + 4);
    float r[8];
    if (MODE == 0) {
        float inv = 1.f / fmaxf(dgf, 1.f);
        half8 sv = ((const half8*)s)[(size_t)wid * 16 + li];
        #pragma unroll
        for (int j = 0; j < 8; ++j)
            r[j] = fmaxf((float)sv[j] + a0[j] * inv + bb[j], 0.f);
    } else {
        float inv = 1.f / (dgf + 1.f);
        half8 gv = g8[(size_t)wid * 16 + li];
        #pragma unroll
        for (int j = 0; j < 8; ++j)
            r[j] = fmaxf((a0[j] + (float)gv[j]) * inv + bb[j], 0.f);
    }
    half8 vhi, vlo;
    #pragma unroll
    for (int j = 0; j < 8; ++j) {
        h16 hi = (h16)r[j];
        vhi[j] = hi;
        vlo[j] = (h16)(r[j] - (float)hi);
    }
    *(half8*)(hhi + (size_t)wid * F + li * 8) = vhi;
    *(half8*)(hlo + (size_t)wid * F + li * 8) = vlo;
}

// ---------------- aggregation d=32 (mean, no relu): padded 16-in-flight ---------
__global__ __launch_bounds__(256) void k_agg32(const h16* __restrict__ g,
        const h16* __restrict__ s, const int* __restrict__ offs,
        const int* __restrict__ csr, const float* __restrict__ degf,
        const float* __restrict__ b, float* __restrict__ out) {
    const int wid  = (int)((blockIdx.x * 256 + threadIdx.x) >> 6);
    const int lane = threadIdx.x & 63;
    if (wid >= NN) return;
    const int grp = lane >> 3;          // 8 row-groups
    const int li  = lane & 7;           // h16x4 slot within the 64B row
    const int beg = offs[wid];
    const float dgf = degf[wid];
    const int n16 = ((int)dgf + 15) >> 4;
    const h16x4* g4 = (const h16x4*)g;  // row stride = 8 h16x4
    float a0[4] = {0.f, 0.f, 0.f, 0.f}, a1[4] = {0.f, 0.f, 0.f, 0.f};
    for (int t = 0; t < n16; ++t) {
        const int e = beg + (t << 4);
        int u0 = csr[e + grp], u1 = csr[e + 8 + grp];
        h16x4 v0 = g4[(size_t)u0 * 8 + li];
        h16x4 v1 = g4[(size_t)u1 * 8 + li];
        #pragma unroll
        for (int j = 0; j < 4; ++j) { a0[j] += (float)v0[j]; a1[j] += (float)v1[j]; }
    }
    #pragma unroll
    for (int j = 0; j < 4; ++j) {
        a0[j] += a1[j];
        a0[j] += __shfl_xor(a0[j], 8, 64);
        a0[j] += __shfl_xor(a0[j], 16, 64);
        a0[j] += __shfl_xor(a0[j], 32, 64);
    }
    if (grp) return;
    const float inv = 1.f / fmaxf(dgf, 1.f);
    float4 bb = ((const float4*)b)[li];
    h16x4 sv = ((const h16x4*)s)[(size_t)wid * 8 + li];
    float4 r;
    r.x = (float)sv[0] + a0[0] * inv + bb.x;
    r.y = (float)sv[1] + a0[1] * inv + bb.y;
    r.z = (float)sv[2] + a0[2] * inv + bb.z;
    r.w = (float)sv[3] + a0[3] * inv + bb.w;
    ((float4*)out)[(size_t)wid * 8 + li] = r;
}

extern "C" void kernel_launch(void* const* d_in, const int* in_sizes, int n_in,
                              void* d_out, int out_size, void* d_ws, size_t ws_size,
                              hipStream_t stream) {
    const float* x       = (const float*)d_in[0];
    const int*   src     = (const int*)  d_in[1];
    const int*   dst     = (const int*)  d_in[2];
    const float* Wself0  = (const float*)d_in[3];
    const float* Wneigh0 = (const float*)d_in[4];
    const float* b0      = (const float*)d_in[5];
    const float* Wneigh1 = (const float*)d_in[6];
    const float* b1      = (const float*)d_in[7];
    const float* Wneigh2 = (const float*)d_in[8];
    const float* b2      = (const float*)d_in[9];
    const float* Wself3  = (const float*)d_in[10];
    const float* Wneigh3 = (const float*)d_in[11];
    const float* b3      = (const float*)d_in[12];
    float* out = (float*)d_out;

    char* ws = (char*)d_ws;
    size_t off = 0;
    auto alloc = [&](size_t bytes) -> void* {
        void* p = ws + off;
        off += (bytes + 255) & ~(size_t)255;
        return p;
    };
    float* degf   = (float*)alloc((size_t)NN * 4);
    int*   offs   = (int*)  alloc((size_t)(NN + 1) * 4);
    int*   csr    = (int*)  alloc((size_t)NBKT * CAP16 * 4);
    int*   bcur   = (int*)  alloc((size_t)NBKT * 4);
    int*   barea  = (int*)  alloc((size_t)NBKT * CAP * 4);
    h16*   hhi    = (h16*)  alloc((size_t)NN * F * 2);
    h16*   hlo    = (h16*)  alloc((size_t)NN * F * 2);
    h16*   s16    = (h16*)  alloc((size_t)NN * F * 2);           // self operand
    h16*   ghA    = (h16*)  alloc((size_t)(NN + 1) * F * 2);     // gather ping (+zero row)
    h16*   ghB    = (h16*)  alloc((size_t)(NN + 1) * F * 2);     // gather pong (+zero row)
    h16*   s16b   = (h16*)  alloc((size_t)NN * FO * 2);          // layer3 self
    h16*   gh4    = (h16*)  alloc((size_t)(NN + 1) * FO * 2);    // layer3 gather (+zero row)
    h16*   WfS0   = (h16*)  alloc((size_t)128 * 128 * 2 * 2);
    h16*   WfN0   = (h16*)  alloc((size_t)128 * 128 * 2 * 2);
    h16*   WfN1   = (h16*)  alloc((size_t)128 * 128 * 2 * 2);
    h16*   WfN2   = (h16*)  alloc((size_t)128 * 128 * 2 * 2);
    h16*   WfS3   = (h16*)  alloc((size_t)128 * 32 * 2 * 2);
    h16*   WfN3   = (h16*)  alloc((size_t)128 * 32 * 2 * 2);

    // 1: weight prep + bucket-cursor zero + sentinel-row zero
    k_pre0<<<289, 256, 0, stream>>>(Wself0, Wneigh0, Wneigh1, Wneigh2,
                                    Wself3, Wneigh3,
                                    WfS0, WfN0, WfN1, WfN2, WfS3, WfN3,
                                    bcur, ghA, ghB, gh4);
    // 2: edge partition ∥ l2norm
    k_pre1<<<NPB + LGRID, 256, 0, stream>>>(src, dst, bcur, barea, x, hhi, hlo);
    // 3: CSR fill (padded) ∥ GEMM0 (h0@S0 -> s16, h0@N0 -> ghA)
    k_bfill_mfma<<<NBKT + MG, 256, 0, stream>>>(barea, bcur, offs, degf, csr,
                                                hhi, hlo, WfS0, WfN0, s16, ghA);
    // 4: agg layer0 (mean)
    k_agg128<0><<<LGRID, 256, 0, stream>>>(ghA, s16, offs, csr, degf, b0, hhi, hlo);
    // 5: GEMM1
    k_mfma<8, 0><<<MG, 256, 0, stream>>>(hhi, hlo, WfN1, nullptr, ghB, nullptr);
    // 6: agg layer1 (gcn)
    k_agg128<1><<<LGRID, 256, 0, stream>>>(ghB, nullptr, offs, csr, degf, b1, hhi, hlo);
    // 7: GEMM2
    k_mfma<8, 0><<<MG, 256, 0, stream>>>(hhi, hlo, WfN2, nullptr, ghA, nullptr);
    // 8: agg layer2 (gcn)
    k_agg128<1><<<LGRID, 256, 0, stream>>>(ghA, nullptr, offs, csr, degf, b2, hhi, hlo);
    // 9: GEMM3 (S3,N3 -> 32 cols each)
    k_mfma<2, 2><<<MG, 256, 0, stream>>>(hhi, hlo, WfS3, WfN3, s16b, gh4);
    // 10: final mean-agg d=32
    k_agg32<<<LGRID, 256, 0, stream>>>(gh4, s16b, offs, csr, degf, b3, out);
}